// Round 13
// baseline (5471.460 us; speedup 1.0000x reference)
//
#include <hip/hip_runtime.h>

typedef __attribute__((ext_vector_type(8))) short s16x8;
typedef __attribute__((ext_vector_type(4))) float fx4;

static __device__ __forceinline__ unsigned short f2bf(float f){
  unsigned u = __float_as_uint(f);
  return (unsigned short)((u + 0x7fffu + ((u>>16)&1u)) >> 16);   // RNE
}
static __device__ __forceinline__ float bf2f(unsigned short s){
  return __uint_as_float(((unsigned)s)<<16);
}
// fast tanh: 1 - 2/(e^{2x}+1). Saturates to +-1, error ~1e-6 << bf16 ulp,
// can NEVER produce NaN (poison-safe). ~6 VALU ops vs libm tanhf's ~60.
static __device__ __forceinline__ float tanh_fast(float x){
  float e = __expf(2.0f*x);
  return 1.0f - 2.0f*__builtin_amdgcn_rcpf(e + 1.0f);
}
// Two 16B LLC-point loads (sc0+sc1 = agent scope: bypass L1 AND L2, read the
// LLC). asm volatile + memory clobber => re-executed every poll iteration.
// R4-R12 lessons: cross-XCD data is only HW-coherent at the LLC; polled
// addresses must be re-read at the LLC each iteration; validity must live IN
// the data (poison), not a separate flag; poll pressure must stay minimal
// (R11); and NOTHING with long latency may share the poll's vmcnt(0).
static __device__ __forceinline__ void ld2_llc(const void* p0, const void* p1,
                                               uint4* o0, uint4* o1){
  uint4 a, b;
  asm volatile("global_load_dwordx4 %0, %2, off sc0 sc1\n\t"
               "global_load_dwordx4 %1, %3, off sc0 sc1\n\t"
               "s_waitcnt vmcnt(0)"
               : "=&v"(a), "=&v"(b) : "v"(p0), "v"(p1) : "memory");
  *o0 = a; *o1 = b;
}

// ---------------------------------------------------------------- W_out -> bf16
__global__ void k_cvt_wout(const float* __restrict__ w, unsigned short* __restrict__ o){
  int g = blockIdx.x*256 + threadIdx.x;
  int idx = g*4;
  float4 f = *(const float4*)(w + idx);
  unsigned u0 = (unsigned)f2bf(f.x) | ((unsigned)f2bf(f.y)<<16);
  unsigned u1 = (unsigned)f2bf(f.z) | ((unsigned)f2bf(f.w)<<16);
  *(uint2*)(o + idx) = make_uint2(u0, u1);
}

// ---------------------------------------------------------------- GEMM1: xp = x@W_ih^T + (b_ih+b_hh)
__global__ __launch_bounds__(256) void k_gemm_xp(
    const float* __restrict__ X, const float* __restrict__ Wih,
    const float* __restrict__ bih, const float* __restrict__ bhh,
    unsigned short* __restrict__ XP){
  __shared__ unsigned short As[128][40];
  __shared__ unsigned short Bs[128][40];
  const int bm = blockIdx.x, bn = blockIdx.y;
  const int tid = threadIdx.x, w = tid>>6, l = tid&63;
  const int wm = w>>1, wn = w&1;
  const int m0 = bm*128, n0 = bn*128;
  fx4 acc[4][4] = {};
  for (int kb = 0; kb < 512; kb += 32){
    #pragma unroll
    for (int q=0;q<4;q++){
      int f = tid + q*256;
      int row = f>>3, c4 = (f&7)*4;
      float4 v = *(const float4*)(X + (m0+row)*512 + kb + c4);
      unsigned u0 = (unsigned)f2bf(v.x) | ((unsigned)f2bf(v.y)<<16);
      unsigned u1 = (unsigned)f2bf(v.z) | ((unsigned)f2bf(v.w)<<16);
      *(uint2*)&As[row][c4] = make_uint2(u0,u1);
    }
    #pragma unroll
    for (int q=0;q<4;q++){
      int f = tid + q*256;
      int row = f>>3, c4 = (f&7)*4;
      float4 v = *(const float4*)(Wih + (n0+row)*512 + kb + c4);
      unsigned u0 = (unsigned)f2bf(v.x) | ((unsigned)f2bf(v.y)<<16);
      unsigned u1 = (unsigned)f2bf(v.z) | ((unsigned)f2bf(v.w)<<16);
      *(uint2*)&Bs[row][c4] = make_uint2(u0,u1);
    }
    __syncthreads();
    const int kbase = (l>>4)*8;
    s16x8 a[4], b[4];
    #pragma unroll
    for (int mt=0;mt<4;mt++) a[mt] = *(const s16x8*)&As[wm*64 + mt*16 + (l&15)][kbase];
    #pragma unroll
    for (int nt=0;nt<4;nt++) b[nt] = *(const s16x8*)&Bs[wn*64 + nt*16 + (l&15)][kbase];
    #pragma unroll
    for (int mt=0;mt<4;mt++)
      #pragma unroll
      for (int nt=0;nt<4;nt++)
        acc[mt][nt] = __builtin_amdgcn_mfma_f32_16x16x32_bf16(a[mt], b[nt], acc[mt][nt], 0,0,0);
    __syncthreads();
  }
  #pragma unroll
  for (int nt=0;nt<4;nt++){
    int n = n0 + wn*64 + nt*16 + (l&15);
    float bias = bih[n] + bhh[n];
    #pragma unroll
    for (int mt=0;mt<4;mt++){
      #pragma unroll
      for (int r=0;r<4;r++){
        int grow = m0 + wm*64 + mt*16 + (l>>4)*4 + r;   // = b*1024 + t
        int bb = grow >> 10, t = grow & 1023;
        XP[(t*64 + bb)*1024 + n] = f2bf(acc[mt][nt][r] + bias);
      }
    }
  }
}

// ---------------------------------------------------------------- recurrence
// R12 structure FROZEN (2320us: poison-poll + self-chunk bypass + tanh_fast).
// ONE change vs R12: the xp prefetch moves from BEFORE the poll to AFTER the
// stage barrier. In the old position the 4 xp loads (HBM misses, ~900cy —
// XP is a 128MB single-pass stream, FETCH_SIZE shows it misses LLC) were
// drained by the first poll iteration's vmcnt(0), serializing HBM latency
// into every step's detect phase. Now they issue under the MFMA block and
// retire before the epilogue consumes them.
// Protocol recap: HS pre-poisoned 0xFFFF (bf16 NaN; tanh can't produce it);
// write-once addresses; sc0+sc1 poll loads re-read the LLC every iteration;
// data self-announces; own-col chunks bypass the LLC via the double-buffered
// LDS. Placement-independent, flag-free, deadlock-impossible.
__global__ __launch_bounds__(512) void k_rnn(
    const float* __restrict__ Whh, const unsigned short* __restrict__ XP,
    unsigned short* __restrict__ HS){
  __shared__ unsigned short hlds[2][8][1032];
  const int wg = blockIdx.x;
  const int gi = wg & 7;            // batch-group (8 rows)
  const int gj = wg >> 3;           // col block (128 cols)
  const int bi = gi*8, cj = gj*128;
  const int tid = threadIdx.x, w = tid>>6, l = tid&63;
  const int kbase = (l>>4)*8;

  // --- W_hh slice as resident MFMA B-fragments (128 VGPR/lane) ---
  const int col = cj + w*16 + (l&15);
  s16x8 wf[32];
  #pragma unroll
  for (int kk=0; kk<32; kk++){
    const float* p = Whh + col*1024 + kk*32 + kbase;
    float4 v0 = *(const float4*)p;
    float4 v1 = *(const float4*)(p+4);
    s16x8 s;
    s[0]=(short)f2bf(v0.x); s[1]=(short)f2bf(v0.y); s[2]=(short)f2bf(v0.z); s[3]=(short)f2bf(v0.w);
    s[4]=(short)f2bf(v1.x); s[5]=(short)f2bf(v1.y); s[6]=(short)f2bf(v1.z); s[7]=(short)f2bf(v1.w);
    wf[kk]=s;
  }

  const int ecol = cj + w*16 + (l&15);

  // --- step 0: h0 = tanh(xp_0); store global (self-announcing) + LDS buf0 ---
  {
    int e = tid*2;
    int row = e>>7, c = e&127;
    unsigned short h0 = f2bf(tanh_fast(bf2f(XP[(bi+row)*1024 + cj + c])));
    unsigned short h1 = f2bf(tanh_fast(bf2f(XP[(bi+row)*1024 + cj + c + 1])));
    unsigned pk = (unsigned)h0 | ((unsigned)h1<<16);
    __hip_atomic_store((unsigned*)&HS[((bi+row)*1024 + 0)*1024 + cj + c], pk,
                       __ATOMIC_RELAXED, __HIP_MEMORY_SCOPE_AGENT);
    hlds[0][row][cj + c]     = h0;       // own chunk pre-staged for step 1
    hlds[0][row][cj + c + 1] = h1;
  }

  const int srow = tid>>6, sc8 = (tid&63)*16;       // staging: thread owns (row, 32B)
  const bool ownchunk = ((unsigned)(sc8 - cj) < 128u); // chunk lies in own cols

  for (int s=1; s<1024; ++s){
    unsigned short (*buf)[1032]  = hlds[(s-1)&1];   // holds h_{s-1}
    unsigned short (*nbuf)[1032] = hlds[s&1];       // receives own h_s
    // --- poison-poll + stage h_{s-1}: peer chunks only (own pre-staged) ---
    if (!ownchunk){
      const unsigned short* rowp = HS + ((bi+srow)*1024 + (s-1))*1024 + sc8;
      uint4 v0, v1;
      for(;;){
        ld2_llc(rowp, rowp+8, &v0, &v1);
        unsigned bad = 0u;
        #pragma unroll
        for (int j=0;j<4;j++){
          unsigned u = ((unsigned*)&v0)[j];
          bad |= (unsigned)((u & 0xFFFFu) == 0xFFFFu) | (unsigned)(u >= 0xFFFF0000u);
        }
        #pragma unroll
        for (int j=0;j<4;j++){
          unsigned u = ((unsigned*)&v1)[j];
          bad |= (unsigned)((u & 0xFFFFu) == 0xFFFFu) | (unsigned)(u >= 0xFFFF0000u);
        }
        if (!bad) break;
      }
      *(uint4*)&buf[srow][sc8]     = v0;
      *(uint4*)&buf[srow][sc8 + 8] = v1;
    }
    __syncthreads();
    // --- xp prefetch: AFTER the barrier, under the MFMA block; consumed in
    //     this step's epilogue. Its HBM latency no longer sits in detect. ---
    float xv[4];
    if (l < 32){
      #pragma unroll
      for (int r=0;r<4;r++)
        xv[r] = bf2f(XP[(s*64 + bi + (l>>4)*4 + r)*1024 + ecol]);
    }
    // --- 32 MFMA, 4 independent chains ---
    const int arow = (l&15)&7;
    fx4 ac0 = {0.f,0.f,0.f,0.f}, ac1 = ac0, ac2 = ac0, ac3 = ac0;
    #pragma unroll
    for (int kk=0;kk<32;kk+=4){
      s16x8 a0 = *(const s16x8*)&buf[arow][(kk+0)*32 + kbase];
      s16x8 a1 = *(const s16x8*)&buf[arow][(kk+1)*32 + kbase];
      s16x8 a2 = *(const s16x8*)&buf[arow][(kk+2)*32 + kbase];
      s16x8 a3 = *(const s16x8*)&buf[arow][(kk+3)*32 + kbase];
      ac0 = __builtin_amdgcn_mfma_f32_16x16x32_bf16(a0, wf[kk+0], ac0, 0,0,0);
      ac1 = __builtin_amdgcn_mfma_f32_16x16x32_bf16(a1, wf[kk+1], ac1, 0,0,0);
      ac2 = __builtin_amdgcn_mfma_f32_16x16x32_bf16(a2, wf[kk+2], ac2, 0,0,0);
      ac3 = __builtin_amdgcn_mfma_f32_16x16x32_bf16(a3, wf[kk+3], ac3, 0,0,0);
    }
    fx4 acc = (ac0+ac1)+(ac2+ac3);
    // --- epilogue: h_s = tanh(acc + xp); sc1 store (self-announcing) +
    //     own-chunk write into next step's LDS buffer ---
    if (l < 32){
      #pragma unroll
      for (int r=0;r<4;r++){
        int row = (l>>4)*4 + r;
        unsigned short hv = f2bf(tanh_fast(acc[r] + xv[r]));
        __hip_atomic_store(&HS[((bi+row)*1024 + s)*1024 + ecol], hv,
                           __ATOMIC_RELAXED, __HIP_MEMORY_SCOPE_AGENT);
        nbuf[row][ecol] = hv;
      }
    }
    // no drain/flag/trailing barrier: next step's poll + barrier order it.
  }
}

// ---------------------------------------------------------------- GEMM2: out = hs@W_out^T + b_out
__global__ __launch_bounds__(512) void k_gemm_out(
    const unsigned short* __restrict__ HS, const unsigned short* __restrict__ WoutB,
    const float* __restrict__ bout, float* __restrict__ OUT){
  __shared__ unsigned short As[128][40];
  __shared__ unsigned short Bs[512][40];
  const int m0 = blockIdx.x*128;
  const int tid = threadIdx.x, w = tid>>6, l = tid&63;
  const int wm = w>>2, wn = w&3;
  fx4 acc[4][8] = {};
  for (int kb = 0; kb < 1024; kb += 32){
    {
      int row = tid>>2, c8 = (tid&3)*8;
      *(uint4*)&As[row][c8] = *(const uint4*)(HS + (m0+row)*1024 + kb + c8);
    }
    #pragma unroll
    for (int q=0;q<4;q++){
      int f = tid + q*512;
      int row = f>>2, c8 = (f&3)*8;
      *(uint4*)&Bs[row][c8] = *(const uint4*)(WoutB + row*1024 + kb + c8);
    }
    __syncthreads();
    const int kbase = (l>>4)*8;
    s16x8 a[4], b[8];
    #pragma unroll
    for (int mt=0;mt<4;mt++) a[mt] = *(const s16x8*)&As[wm*64 + mt*16 + (l&15)][kbase];
    #pragma unroll
    for (int nt=0;nt<8;nt++) b[nt] = *(const s16x8*)&Bs[wn*128 + nt*16 + (l&15)][kbase];
    #pragma unroll
    for (int mt=0;mt<4;mt++)
      #pragma unroll
      for (int nt=0;nt<8;nt++)
        acc[mt][nt] = __builtin_amdgcn_mfma_f32_16x16x32_bf16(a[mt], b[nt], acc[mt][nt], 0,0,0);
    __syncthreads();
  }
  #pragma unroll
  for (int nt=0;nt<8;nt++){
    int n = wn*128 + nt*16 + (l&15);
    float bias = bout[n];
    #pragma unroll
    for (int mt=0;mt<4;mt++){
      #pragma unroll
      for (int r=0;r<4;r++){
        int row = m0 + wm*64 + mt*16 + (l>>4)*4 + r;
        OUT[row*512 + n] = acc[mt][nt][r] + bias;
      }
    }
  }
}

// ---------------------------------------------------------------- launch
extern "C" void kernel_launch(void* const* d_in, const int* in_sizes, int n_in,
                              void* d_out, int out_size, void* d_ws, size_t ws_size,
                              hipStream_t stream){
  const float* x    = (const float*)d_in[0];
  const float* Wih  = (const float*)d_in[1];
  const float* Whh  = (const float*)d_in[2];
  const float* bih  = (const float*)d_in[3];
  const float* bhh  = (const float*)d_in[4];
  const float* Wout = (const float*)d_in[5];
  const float* bout = (const float*)d_in[6];

  const size_t XP_BYTES = 134217728ull;            // bf16 xp, [T][B][H]
  unsigned short* XP    = (unsigned short*)d_ws;
  unsigned short* WoutB = (unsigned short*)((char*)d_ws + XP_BYTES);
  unsigned short* HS    = (unsigned short*)d_out;  // hs bf16 lives in d_out
  float*          OUT   = (float*)d_out;

  k_cvt_wout<<<512, 256, 0, stream>>>(Wout, WoutB);
  dim3 g1(512, 8);
  k_gemm_xp<<<g1, 256, 0, stream>>>(x, Wih, bih, bhh, XP);
  // poison HS: 0xFF bytes -> every bf16 short is NaN (0xFFFF); tanh output
  // can never be NaN, so non-poison == final value (self-announcing data).
  hipMemsetAsync(HS, 0xFF, 134217728ull, stream);
  k_rnn<<<64, 512, 0, stream>>>(Whh, XP, HS);
  k_gemm_out<<<512, 512, 0, stream>>>(HS, WoutB, bout, OUT);
}

// Round 14
// 3056.391 us; speedup vs baseline: 1.7902x; 1.7902x over previous
//
#include <hip/hip_runtime.h>

typedef __attribute__((ext_vector_type(8))) short s16x8;
typedef __attribute__((ext_vector_type(4))) float fx4;

static __device__ __forceinline__ unsigned short f2bf(float f){
  unsigned u = __float_as_uint(f);
  return (unsigned short)((u + 0x7fffu + ((u>>16)&1u)) >> 16);   // RNE
}
static __device__ __forceinline__ float bf2f(unsigned short s){
  return __uint_as_float(((unsigned)s)<<16);
}
// fast tanh: 1 - 2/(e^{2x}+1). Saturates to +-1, error ~1e-6 << bf16 ulp.
static __device__ __forceinline__ float tanh_fast(float x){
  float e = __expf(2.0f*x);
  return 1.0f - 2.0f*__builtin_amdgcn_rcpf(e + 1.0f);
}
// Four 16B LLC-point loads (sc0+sc1 = bypass L1 AND L2, read the LLC).
// R4-R13 lessons: cross-XCD data is only HW-coherent at the LLC; polled
// addresses must be re-read at the LLC every iteration; validity must live
// IN the polled word (tag/poison), not a separate flag; poll pressure must
// stay minimal; and the polled lines must be LLC-RESIDENT — R13 showed
// poll misses on LLC-evicted lines cost ~900cy HBM fetches (+85MB FETCH).
static __device__ __forceinline__ void ld4_llc(const void* p, uint4* o0,
                                               uint4* o1, uint4* o2, uint4* o3){
  uint4 a, b, c, d;
  asm volatile("global_load_dwordx4 %0, %4, off sc0 sc1\n\t"
               "global_load_dwordx4 %1, %4, off offset:16 sc0 sc1\n\t"
               "global_load_dwordx4 %2, %4, off offset:32 sc0 sc1\n\t"
               "global_load_dwordx4 %3, %4, off offset:48 sc0 sc1\n\t"
               "s_waitcnt vmcnt(0)"
               : "=&v"(a), "=&v"(b), "=&v"(c), "=&v"(d) : "v"(p) : "memory");
  *o0 = a; *o1 = b; *o2 = c; *o3 = d;
}

// ---------------------------------------------------------------- GEMM1: xp = x@W_ih^T + (b_ih+b_hh)
__global__ __launch_bounds__(256) void k_gemm_xp(
    const float* __restrict__ X, const float* __restrict__ Wih,
    const float* __restrict__ bih, const float* __restrict__ bhh,
    unsigned short* __restrict__ XP){
  __shared__ unsigned short As[128][40];
  __shared__ unsigned short Bs[128][40];
  const int bm = blockIdx.x, bn = blockIdx.y;
  const int tid = threadIdx.x, w = tid>>6, l = tid&63;
  const int wm = w>>1, wn = w&1;
  const int m0 = bm*128, n0 = bn*128;
  fx4 acc[4][4] = {};
  for (int kb = 0; kb < 512; kb += 32){
    #pragma unroll
    for (int q=0;q<4;q++){
      int f = tid + q*256;
      int row = f>>3, c4 = (f&7)*4;
      float4 v = *(const float4*)(X + (m0+row)*512 + kb + c4);
      unsigned u0 = (unsigned)f2bf(v.x) | ((unsigned)f2bf(v.y)<<16);
      unsigned u1 = (unsigned)f2bf(v.z) | ((unsigned)f2bf(v.w)<<16);
      *(uint2*)&As[row][c4] = make_uint2(u0,u1);
    }
    #pragma unroll
    for (int q=0;q<4;q++){
      int f = tid + q*256;
      int row = f>>3, c4 = (f&7)*4;
      float4 v = *(const float4*)(Wih + (n0+row)*512 + kb + c4);
      unsigned u0 = (unsigned)f2bf(v.x) | ((unsigned)f2bf(v.y)<<16);
      unsigned u1 = (unsigned)f2bf(v.z) | ((unsigned)f2bf(v.w)<<16);
      *(uint2*)&Bs[row][c4] = make_uint2(u0,u1);
    }
    __syncthreads();
    const int kbase = (l>>4)*8;
    s16x8 a[4], b[4];
    #pragma unroll
    for (int mt=0;mt<4;mt++) a[mt] = *(const s16x8*)&As[wm*64 + mt*16 + (l&15)][kbase];
    #pragma unroll
    for (int nt=0;nt<4;nt++) b[nt] = *(const s16x8*)&Bs[wn*64 + nt*16 + (l&15)][kbase];
    #pragma unroll
    for (int mt=0;mt<4;mt++)
      #pragma unroll
      for (int nt=0;nt<4;nt++)
        acc[mt][nt] = __builtin_amdgcn_mfma_f32_16x16x32_bf16(a[mt], b[nt], acc[mt][nt], 0,0,0);
    __syncthreads();
  }
  #pragma unroll
  for (int nt=0;nt<4;nt++){
    int n = n0 + wn*64 + nt*16 + (l&15);
    float bias = bih[n] + bhh[n];
    #pragma unroll
    for (int mt=0;mt<4;mt++){
      #pragma unroll
      for (int r=0;r<4;r++){
        int grow = m0 + wm*64 + mt*16 + (l>>4)*4 + r;   // = b*1024 + t
        int bb = grow >> 10, t = grow & 1023;
        XP[(t*64 + bb)*1024 + n] = f2bf(acc[mt][nt][r] + bias);
      }
    }
  }
}

// ---------------------------------------------------------------- recurrence
// R12 schedule FROZEN (xp-prefetch-before-poll, self-chunk bypass, dbuf LDS,
// 32-MFMA, 64x512 grid). ONE structural change: the rendezvous surface moves
// from the 128MB HS array (LLC-evicted -> poll misses cost HBM fetches, R13)
// to a 1MB ROTATING TAGGED MAILBOX (4 slots x 64 rows x 1024 cols, dword =
// (h_bf16<<16)|step_tag), which stays LLC-resident:
//   producer: 4 sc1 tagged-dword stores to MB slot s&3 (+ plain HS stores,
//             write-only, read by gemm_out after kernel boundary).
//   consumer: polls its 64B of MB slot (s-1)&3 with sc0+sc1 loads until all
//             16 tags == s-1, extracts h from high halves, stages LDS.
// Slot-reuse safety (D=4): a producer overwrites slot k=s&3 at step s+4 only
// after passing step s+4's poll => all peers published s+3 => monotonically
// they completed staging of step s+1, which read slot s&3. Tag mismatch is
// detectable (s-4 != s), so correctness never depends on timing; liveness is
// inductive as before. Flag-free, placement-independent, deadlock-impossible.
__global__ __launch_bounds__(512) void k_rnn(
    const float* __restrict__ Whh, const unsigned short* __restrict__ XP,
    unsigned short* __restrict__ HS, unsigned* __restrict__ MB){
  __shared__ unsigned short hlds[2][8][1032];
  const int wg = blockIdx.x;
  const int gi = wg & 7;            // batch-group (8 rows)
  const int gj = wg >> 3;           // col block (128 cols)
  const int bi = gi*8, cj = gj*128;
  const int tid = threadIdx.x, w = tid>>6, l = tid&63;
  const int kbase = (l>>4)*8;

  // --- W_hh slice as resident MFMA B-fragments (128 VGPR/lane) ---
  const int col = cj + w*16 + (l&15);
  s16x8 wf[32];
  #pragma unroll
  for (int kk=0; kk<32; kk++){
    const float* p = Whh + col*1024 + kk*32 + kbase;
    float4 v0 = *(const float4*)p;
    float4 v1 = *(const float4*)(p+4);
    s16x8 s;
    s[0]=(short)f2bf(v0.x); s[1]=(short)f2bf(v0.y); s[2]=(short)f2bf(v0.z); s[3]=(short)f2bf(v0.w);
    s[4]=(short)f2bf(v1.x); s[5]=(short)f2bf(v1.y); s[6]=(short)f2bf(v1.z); s[7]=(short)f2bf(v1.w);
    wf[kk]=s;
  }

  const int ecol = cj + w*16 + (l&15);

  // --- step 0: h0 = tanh(xp_0); mailbox (tag 0) + plain HS + LDS buf0 ---
  {
    int e = tid*2;
    int row = e>>7, c = e&127;
    int grow = bi + row;
    unsigned short h0 = f2bf(tanh_fast(bf2f(XP[grow*1024 + cj + c])));
    unsigned short h1 = f2bf(tanh_fast(bf2f(XP[grow*1024 + cj + c + 1])));
    unsigned long long mv = ((unsigned long long)(((unsigned)h1<<16)) << 32)
                          |  (unsigned long long)(((unsigned)h0<<16));
    __hip_atomic_store((unsigned long long*)&MB[grow*1024 + cj + c], mv,
                       __ATOMIC_RELAXED, __HIP_MEMORY_SCOPE_AGENT);
    *(unsigned*)&HS[(grow*1024 + 0)*1024 + cj + c] =
        (unsigned)h0 | ((unsigned)h1<<16);             // plain, write-only
    hlds[0][row][cj + c]     = h0;                     // own chunk pre-staged
    hlds[0][row][cj + c + 1] = h1;
  }

  const int srow = tid>>6;                // staging row 0..7
  const int sd0  = (tid&63)*16;           // dword col base (16 dwords = 64B)
  const bool ownchunk = ((unsigned)(sd0 - cj) < 128u);

  for (int s=1; s<1024; ++s){
    // --- xp prefetch BEFORE the poll (R12-proven position: acts as commit
    //     delay + free overlap; retired during the first poll iteration) ---
    float xv[4];
    if (l < 32){
      #pragma unroll
      for (int r=0;r<4;r++)
        xv[r] = bf2f(XP[(s*64 + bi + (l>>4)*4 + r)*1024 + ecol]);
    }
    unsigned short (*buf)[1032]  = hlds[(s-1)&1];   // holds h_{s-1}
    unsigned short (*nbuf)[1032] = hlds[s&1];       // receives own h_s
    // --- tag-poll + stage h_{s-1}: peer chunks only (LLC-hot mailbox) ---
    if (!ownchunk){
      const unsigned* mp = MB + (((s-1)&3)*64 + bi + srow)*1024 + sd0;
      const unsigned tag = (unsigned)(s-1);
      uint4 v0, v1, v2, v3;
      for(;;){
        ld4_llc(mp, &v0, &v1, &v2, &v3);
        unsigned bad = 0u;
        #pragma unroll
        for (int j=0;j<4;j++) bad |= (((unsigned*)&v0)[j] ^ tag) & 0xFFFFu;
        #pragma unroll
        for (int j=0;j<4;j++) bad |= (((unsigned*)&v1)[j] ^ tag) & 0xFFFFu;
        #pragma unroll
        for (int j=0;j<4;j++) bad |= (((unsigned*)&v2)[j] ^ tag) & 0xFFFFu;
        #pragma unroll
        for (int j=0;j<4;j++) bad |= (((unsigned*)&v3)[j] ^ tag) & 0xFFFFu;
        if (!bad) break;
      }
      // extract h (high halves) -> 16 shorts
      uint4 p0, p1;
      p0.x = (v0.x>>16) | (v0.y & 0xFFFF0000u);
      p0.y = (v0.z>>16) | (v0.w & 0xFFFF0000u);
      p0.z = (v1.x>>16) | (v1.y & 0xFFFF0000u);
      p0.w = (v1.z>>16) | (v1.w & 0xFFFF0000u);
      p1.x = (v2.x>>16) | (v2.y & 0xFFFF0000u);
      p1.y = (v2.z>>16) | (v2.w & 0xFFFF0000u);
      p1.z = (v3.x>>16) | (v3.y & 0xFFFF0000u);
      p1.w = (v3.z>>16) | (v3.w & 0xFFFF0000u);
      *(uint4*)&buf[srow][sd0]     = p0;
      *(uint4*)&buf[srow][sd0 + 8] = p1;
    }
    __syncthreads();
    // --- 32 MFMA, 4 independent chains ---
    const int arow = (l&15)&7;
    fx4 ac0 = {0.f,0.f,0.f,0.f}, ac1 = ac0, ac2 = ac0, ac3 = ac0;
    #pragma unroll
    for (int kk=0;kk<32;kk+=4){
      s16x8 a0 = *(const s16x8*)&buf[arow][(kk+0)*32 + kbase];
      s16x8 a1 = *(const s16x8*)&buf[arow][(kk+1)*32 + kbase];
      s16x8 a2 = *(const s16x8*)&buf[arow][(kk+2)*32 + kbase];
      s16x8 a3 = *(const s16x8*)&buf[arow][(kk+3)*32 + kbase];
      ac0 = __builtin_amdgcn_mfma_f32_16x16x32_bf16(a0, wf[kk+0], ac0, 0,0,0);
      ac1 = __builtin_amdgcn_mfma_f32_16x16x32_bf16(a1, wf[kk+1], ac1, 0,0,0);
      ac2 = __builtin_amdgcn_mfma_f32_16x16x32_bf16(a2, wf[kk+2], ac2, 0,0,0);
      ac3 = __builtin_amdgcn_mfma_f32_16x16x32_bf16(a3, wf[kk+3], ac3, 0,0,0);
    }
    fx4 acc = (ac0+ac1)+(ac2+ac3);
    // --- epilogue: h_s = tanh(acc + xp); tagged mailbox sc1 store + plain
    //     HS store + own-chunk write into next step's LDS buffer ---
    if (l < 32){
      #pragma unroll
      for (int r=0;r<4;r++){
        int row = (l>>4)*4 + r;
        int grow = bi + row;
        unsigned short hv = f2bf(tanh_fast(acc[r] + xv[r]));
        __hip_atomic_store(&MB[((s&3)*64 + grow)*1024 + ecol],
                           ((unsigned)hv<<16) | (unsigned)s,
                           __ATOMIC_RELAXED, __HIP_MEMORY_SCOPE_AGENT);
        HS[(grow*1024 + s)*1024 + ecol] = hv;          // plain, write-only
        nbuf[row][ecol] = hv;
      }
    }
    // no drain/flag/trailing barrier: next step's poll + barrier order it.
  }
}

// ---------------------------------------------------------------- GEMM2: out = hs@W_out^T + b_out
// B staged from f32 W_out with inline f32->bf16 convert (cvt kernel dropped
// to keep ws high-water <= proven bound; W_out is 2MB, L2/LLC-hot).
__global__ __launch_bounds__(512) void k_gemm_out(
    const unsigned short* __restrict__ HS, const float* __restrict__ Wout,
    const float* __restrict__ bout, float* __restrict__ OUT){
  __shared__ unsigned short As[128][40];
  __shared__ unsigned short Bs[512][40];
  const int m0 = blockIdx.x*128;
  const int tid = threadIdx.x, w = tid>>6, l = tid&63;
  const int wm = w>>2, wn = w&3;
  fx4 acc[4][8] = {};
  for (int kb = 0; kb < 1024; kb += 32){
    {
      int row = tid>>2, c8 = (tid&3)*8;
      *(uint4*)&As[row][c8] = *(const uint4*)(HS + (m0+row)*1024 + kb + c8);
    }
    #pragma unroll
    for (int q=0;q<4;q++){
      int f = tid + q*512;
      int row = f>>2, c8 = (f&3)*8;
      float4 va = *(const float4*)(Wout + row*1024 + kb + c8);
      float4 vb = *(const float4*)(Wout + row*1024 + kb + c8 + 4);
      uint4 u;
      u.x = (unsigned)f2bf(va.x) | ((unsigned)f2bf(va.y)<<16);
      u.y = (unsigned)f2bf(va.z) | ((unsigned)f2bf(va.w)<<16);
      u.z = (unsigned)f2bf(vb.x) | ((unsigned)f2bf(vb.y)<<16);
      u.w = (unsigned)f2bf(vb.z) | ((unsigned)f2bf(vb.w)<<16);
      *(uint4*)&Bs[row][c8] = u;
    }
    __syncthreads();
    const int kbase = (l>>4)*8;
    s16x8 a[4], b[8];
    #pragma unroll
    for (int mt=0;mt<4;mt++) a[mt] = *(const s16x8*)&As[wm*64 + mt*16 + (l&15)][kbase];
    #pragma unroll
    for (int nt=0;nt<8;nt++) b[nt] = *(const s16x8*)&Bs[wn*128 + nt*16 + (l&15)][kbase];
    #pragma unroll
    for (int mt=0;mt<4;mt++)
      #pragma unroll
      for (int nt=0;nt<8;nt++)
        acc[mt][nt] = __builtin_amdgcn_mfma_f32_16x16x32_bf16(a[mt], b[nt], acc[mt][nt], 0,0,0);
    __syncthreads();
  }
  #pragma unroll
  for (int nt=0;nt<8;nt++){
    int n = wn*128 + nt*16 + (l&15);
    float bias = bout[n];
    #pragma unroll
    for (int mt=0;mt<4;mt++){
      #pragma unroll
      for (int r=0;r<4;r++){
        int row = m0 + wm*64 + mt*16 + (l>>4)*4 + r;
        OUT[row*512 + n] = acc[mt][nt][r] + bias;
      }
    }
  }
}

// ---------------------------------------------------------------- launch
extern "C" void kernel_launch(void* const* d_in, const int* in_sizes, int n_in,
                              void* d_out, int out_size, void* d_ws, size_t ws_size,
                              hipStream_t stream){
  const float* x    = (const float*)d_in[0];
  const float* Wih  = (const float*)d_in[1];
  const float* Whh  = (const float*)d_in[2];
  const float* bih  = (const float*)d_in[3];
  const float* bhh  = (const float*)d_in[4];
  const float* Wout = (const float*)d_in[5];
  const float* bout = (const float*)d_in[6];

  const size_t XP_BYTES = 134217728ull;            // bf16 xp, [T][B][H]
  unsigned short* XP = (unsigned short*)d_ws;
  unsigned*       MB = (unsigned*)((char*)d_ws + XP_BYTES);  // 1MB mailbox
  unsigned short* HS = (unsigned short*)d_out;     // hs bf16 lives in d_out
  float*          OUT= (float*)d_out;

  // poison mailbox: 0xFF bytes -> tag 0xFFFF, never equals any s in [0,1024)
  hipMemsetAsync(MB, 0xFF, 1048576ull, stream);
  dim3 g1(512, 8);
  k_gemm_xp<<<g1, 256, 0, stream>>>(x, Wih, bih, bhh, XP);
  k_rnn<<<64, 512, 0, stream>>>(Whh, XP, HS, MB);
  k_gemm_out<<<512, 512, 0, stream>>>(HS, Wout, bout, OUT);
}

// Round 16
// 3038.914 us; speedup vs baseline: 1.8005x; 1.0058x over previous
//
#include <hip/hip_runtime.h>

typedef __attribute__((ext_vector_type(8))) short s16x8;
typedef __attribute__((ext_vector_type(4))) float fx4;

static __device__ __forceinline__ unsigned short f2bf(float f){
  unsigned u = __float_as_uint(f);
  return (unsigned short)((u + 0x7fffu + ((u>>16)&1u)) >> 16);   // RNE
}
static __device__ __forceinline__ float bf2f(unsigned short s){
  return __uint_as_float(((unsigned)s)<<16);
}
// fast tanh: 1 - 2/(e^{2x}+1). Saturates to +-1, error ~1e-6 << bf16 ulp,
// can NEVER produce NaN (poison-safe).
static __device__ __forceinline__ float tanh_fast(float x){
  float e = __expf(2.0f*x);
  return 1.0f - 2.0f*__builtin_amdgcn_rcpf(e + 1.0f);
}
// Two 16B LLC-point loads (sc0+sc1: bypass L1 AND L2, read the LLC).
// R4-R14 lessons: cross-XCD data is only HW-coherent at the LLC; polled
// addresses must be re-read at the LLC every iteration; validity lives IN
// the data (poison); poll pressure minimal; recently-written lines are the
// only LLC-resident rendezvous surface (R14: aged lines evict -> HBM polls).
// NOTE (R15): uint4 works as an inline-asm OUTPUT ("=&v") but NOT as an
// input ("v") — hipcc rejects 128-bit indirect register inputs. Wide sc1
// STORES must therefore go through __hip_atomic_store<u64> (emits
// global_store_dwordx2 sc1), not inline asm.
static __device__ __forceinline__ void ld2_llc(const void* p0, const void* p1,
                                               uint4* o0, uint4* o1){
  uint4 a, b;
  asm volatile("global_load_dwordx4 %0, %2, off sc0 sc1\n\t"
               "global_load_dwordx4 %1, %3, off sc0 sc1\n\t"
               "s_waitcnt vmcnt(0)"
               : "=&v"(a), "=&v"(b) : "v"(p0), "v"(p1) : "memory");
  *o0 = a; *o1 = b;
}

// ---------------------------------------------------------------- W_out -> bf16
__global__ void k_cvt_wout(const float* __restrict__ w, unsigned short* __restrict__ o){
  int g = blockIdx.x*256 + threadIdx.x;
  int idx = g*4;
  float4 f = *(const float4*)(w + idx);
  unsigned u0 = (unsigned)f2bf(f.x) | ((unsigned)f2bf(f.y)<<16);
  unsigned u1 = (unsigned)f2bf(f.z) | ((unsigned)f2bf(f.w)<<16);
  *(uint2*)(o + idx) = make_uint2(u0, u1);
}

// ---------------------------------------------------------------- GEMM1: xp = x@W_ih^T + (b_ih+b_hh)
__global__ __launch_bounds__(256) void k_gemm_xp(
    const float* __restrict__ X, const float* __restrict__ Wih,
    const float* __restrict__ bih, const float* __restrict__ bhh,
    unsigned short* __restrict__ XP){
  __shared__ unsigned short As[128][40];
  __shared__ unsigned short Bs[128][40];
  const int bm = blockIdx.x, bn = blockIdx.y;
  const int tid = threadIdx.x, w = tid>>6, l = tid&63;
  const int wm = w>>1, wn = w&1;
  const int m0 = bm*128, n0 = bn*128;
  fx4 acc[4][4] = {};
  for (int kb = 0; kb < 512; kb += 32){
    #pragma unroll
    for (int q=0;q<4;q++){
      int f = tid + q*256;
      int row = f>>3, c4 = (f&7)*4;
      float4 v = *(const float4*)(X + (m0+row)*512 + kb + c4);
      unsigned u0 = (unsigned)f2bf(v.x) | ((unsigned)f2bf(v.y)<<16);
      unsigned u1 = (unsigned)f2bf(v.z) | ((unsigned)f2bf(v.w)<<16);
      *(uint2*)&As[row][c4] = make_uint2(u0,u1);
    }
    #pragma unroll
    for (int q=0;q<4;q++){
      int f = tid + q*256;
      int row = f>>3, c4 = (f&7)*4;
      float4 v = *(const float4*)(Wih + (n0+row)*512 + kb + c4);
      unsigned u0 = (unsigned)f2bf(v.x) | ((unsigned)f2bf(v.y)<<16);
      unsigned u1 = (unsigned)f2bf(v.z) | ((unsigned)f2bf(v.w)<<16);
      *(uint2*)&Bs[row][c4] = make_uint2(u0,u1);
    }
    __syncthreads();
    const int kbase = (l>>4)*8;
    s16x8 a[4], b[4];
    #pragma unroll
    for (int mt=0;mt<4;mt++) a[mt] = *(const s16x8*)&As[wm*64 + mt*16 + (l&15)][kbase];
    #pragma unroll
    for (int nt=0;nt<4;nt++) b[nt] = *(const s16x8*)&Bs[wn*64 + nt*16 + (l&15)][kbase];
    #pragma unroll
    for (int mt=0;mt<4;mt++)
      #pragma unroll
      for (int nt=0;nt<4;nt++)
        acc[mt][nt] = __builtin_amdgcn_mfma_f32_16x16x32_bf16(a[mt], b[nt], acc[mt][nt], 0,0,0);
    __syncthreads();
  }
  #pragma unroll
  for (int nt=0;nt<4;nt++){
    int n = n0 + wn*64 + nt*16 + (l&15);
    float bias = bih[n] + bhh[n];
    #pragma unroll
    for (int mt=0;mt<4;mt++){
      #pragma unroll
      for (int r=0;r<4;r++){
        int grow = m0 + wm*64 + mt*16 + (l>>4)*4 + r;   // = b*1024 + t
        int bb = grow >> 10, t = grow & 1023;
        XP[(t*64 + bb)*1024 + n] = f2bf(acc[mt][nt][r] + bias);
      }
    }
  }
}

// ---------------------------------------------------------------- recurrence
// R12 FROZEN (2320us: poison-poll + self-chunk bypass + tanh_fast +
// xp-prefetch-before-poll as store-drain cover). ONE change: PACKED COMMIT.
// R12's epilogue published h via 1024 scattered 2B sc1 stores per WG per
// step (16-col-stride pattern -> ~256 partial 32B-sector LLC transactions,
// commit of the last one sits on the handoff chain). Now the epilogue only
// writes nbuf (LDS); after a barrier the 64 own-chunk threads publish the
// WG's 2KB as 4x8B sc1 atomic stores each (256 dwordx2, 8 full 256B row
// segments). Far fewer LLC write transactions, no partial sectors.
// Race-check: wide-store threads read OWN chunks of nbuf; the next
// iteration's staging writes only PEER chunks of that same parity buffer
// (disjoint); epilogue s+1 writes the other parity buffer.
// Protocol recap: HS pre-poisoned 0xFFFF (bf16 NaN; tanh can't produce it);
// write-once addresses; sc0+sc1 poll loads re-read the LLC every iteration;
// data self-announces. Placement-independent, flag-free, deadlock-impossible.
__global__ __launch_bounds__(512) void k_rnn(
    const float* __restrict__ Whh, const unsigned short* __restrict__ XP,
    unsigned short* __restrict__ HS){
  __shared__ unsigned short hlds[2][8][1032];
  const int wg = blockIdx.x;
  const int gi = wg & 7;            // batch-group (8 rows)
  const int gj = wg >> 3;           // col block (128 cols)
  const int bi = gi*8, cj = gj*128;
  const int tid = threadIdx.x, w = tid>>6, l = tid&63;
  const int kbase = (l>>4)*8;

  // --- W_hh slice as resident MFMA B-fragments (128 VGPR/lane) ---
  const int col = cj + w*16 + (l&15);
  s16x8 wf[32];
  #pragma unroll
  for (int kk=0; kk<32; kk++){
    const float* p = Whh + col*1024 + kk*32 + kbase;
    float4 v0 = *(const float4*)p;
    float4 v1 = *(const float4*)(p+4);
    s16x8 s;
    s[0]=(short)f2bf(v0.x); s[1]=(short)f2bf(v0.y); s[2]=(short)f2bf(v0.z); s[3]=(short)f2bf(v0.w);
    s[4]=(short)f2bf(v1.x); s[5]=(short)f2bf(v1.y); s[6]=(short)f2bf(v1.z); s[7]=(short)f2bf(v1.w);
    wf[kk]=s;
  }

  const int ecol = cj + w*16 + (l&15);

  // --- step 0: h0 = tanh(xp_0); sc1 dword stores (already packed) + buf0 ---
  {
    int e = tid*2;
    int row = e>>7, c = e&127;
    unsigned short h0 = f2bf(tanh_fast(bf2f(XP[(bi+row)*1024 + cj + c])));
    unsigned short h1 = f2bf(tanh_fast(bf2f(XP[(bi+row)*1024 + cj + c + 1])));
    unsigned pk = (unsigned)h0 | ((unsigned)h1<<16);
    __hip_atomic_store((unsigned*)&HS[((bi+row)*1024 + 0)*1024 + cj + c], pk,
                       __ATOMIC_RELAXED, __HIP_MEMORY_SCOPE_AGENT);
    hlds[0][row][cj + c]     = h0;       // own chunk pre-staged for step 1
    hlds[0][row][cj + c + 1] = h1;
  }

  const int srow = tid>>6, sc8 = (tid&63)*16;       // staging: thread owns (row, 32B)
  const bool ownchunk = ((unsigned)(sc8 - cj) < 128u); // chunk lies in own cols

  for (int s=1; s<1024; ++s){
    // --- xp prefetch BEFORE the poll (R12-proven: covers the drain of the
    //     just-issued wide stores and delays the first poll iteration) ---
    float xv[4];
    if (l < 32){
      #pragma unroll
      for (int r=0;r<4;r++)
        xv[r] = bf2f(XP[(s*64 + bi + (l>>4)*4 + r)*1024 + ecol]);
    }
    unsigned short (*buf)[1032]  = hlds[(s-1)&1];   // holds h_{s-1}
    unsigned short (*nbuf)[1032] = hlds[s&1];       // receives own h_s
    // --- poison-poll + stage h_{s-1}: peer chunks only (own pre-staged) ---
    if (!ownchunk){
      const unsigned short* rowp = HS + ((bi+srow)*1024 + (s-1))*1024 + sc8;
      uint4 v0, v1;
      for(;;){
        ld2_llc(rowp, rowp+8, &v0, &v1);
        unsigned bad = 0u;
        #pragma unroll
        for (int j=0;j<4;j++){
          unsigned u = ((unsigned*)&v0)[j];
          bad |= (unsigned)((u & 0xFFFFu) == 0xFFFFu) | (unsigned)(u >= 0xFFFF0000u);
        }
        #pragma unroll
        for (int j=0;j<4;j++){
          unsigned u = ((unsigned*)&v1)[j];
          bad |= (unsigned)((u & 0xFFFFu) == 0xFFFFu) | (unsigned)(u >= 0xFFFF0000u);
        }
        if (!bad) break;
      }
      *(uint4*)&buf[srow][sc8]     = v0;
      *(uint4*)&buf[srow][sc8 + 8] = v1;
    }
    __syncthreads();
    // --- 32 MFMA, 4 independent chains ---
    const int arow = (l&15)&7;
    fx4 ac0 = {0.f,0.f,0.f,0.f}, ac1 = ac0, ac2 = ac0, ac3 = ac0;
    #pragma unroll
    for (int kk=0;kk<32;kk+=4){
      s16x8 a0 = *(const s16x8*)&buf[arow][(kk+0)*32 + kbase];
      s16x8 a1 = *(const s16x8*)&buf[arow][(kk+1)*32 + kbase];
      s16x8 a2 = *(const s16x8*)&buf[arow][(kk+2)*32 + kbase];
      s16x8 a3 = *(const s16x8*)&buf[arow][(kk+3)*32 + kbase];
      ac0 = __builtin_amdgcn_mfma_f32_16x16x32_bf16(a0, wf[kk+0], ac0, 0,0,0);
      ac1 = __builtin_amdgcn_mfma_f32_16x16x32_bf16(a1, wf[kk+1], ac1, 0,0,0);
      ac2 = __builtin_amdgcn_mfma_f32_16x16x32_bf16(a2, wf[kk+2], ac2, 0,0,0);
      ac3 = __builtin_amdgcn_mfma_f32_16x16x32_bf16(a3, wf[kk+3], ac3, 0,0,0);
    }
    fx4 acc = (ac0+ac1)+(ac2+ac3);
    // --- epilogue: h_s = tanh(acc + xp) -> LDS nbuf ONLY (no global) ---
    if (l < 32){
      #pragma unroll
      for (int r=0;r<4;r++){
        int row = (l>>4)*4 + r;
        nbuf[row][ecol] = f2bf(tanh_fast(acc[r] + xv[r]));
      }
    }
    __syncthreads();
    // --- PACKED COMMIT: own-chunk threads publish 32B each (4x8B sc1) ---
    if (ownchunk){
      const unsigned long long* src = (const unsigned long long*)&nbuf[srow][sc8];
      unsigned long long* dst =
          (unsigned long long*)(HS + ((bi+srow)*1024 + s)*1024 + sc8);
      #pragma unroll
      for (int j=0;j<4;j++)
        __hip_atomic_store(dst + j, src[j],
                           __ATOMIC_RELAXED, __HIP_MEMORY_SCOPE_AGENT);
    }
    // stores drain under next iteration's xp prefetch + first poll vmcnt.
  }
}

// ---------------------------------------------------------------- GEMM2: out = hs@W_out^T + b_out
__global__ __launch_bounds__(512) void k_gemm_out(
    const unsigned short* __restrict__ HS, const unsigned short* __restrict__ WoutB,
    const float* __restrict__ bout, float* __restrict__ OUT){
  __shared__ unsigned short As[128][40];
  __shared__ unsigned short Bs[512][40];
  const int m0 = blockIdx.x*128;
  const int tid = threadIdx.x, w = tid>>6, l = tid&63;
  const int wm = w>>2, wn = w&3;
  fx4 acc[4][8] = {};
  for (int kb = 0; kb < 1024; kb += 32){
    {
      int row = tid>>2, c8 = (tid&3)*8;
      *(uint4*)&As[row][c8] = *(const uint4*)(HS + (m0+row)*1024 + kb + c8);
    }
    #pragma unroll
    for (int q=0;q<4;q++){
      int f = tid + q*512;
      int row = f>>2, c8 = (f&3)*8;
      *(uint4*)&Bs[row][c8] = *(const uint4*)(WoutB + row*1024 + kb + c8);
    }
    __syncthreads();
    const int kbase = (l>>4)*8;
    s16x8 a[4], b[8];
    #pragma unroll
    for (int mt=0;mt<4;mt++) a[mt] = *(const s16x8*)&As[wm*64 + mt*16 + (l&15)][kbase];
    #pragma unroll
    for (int nt=0;nt<8;nt++) b[nt] = *(const s16x8*)&Bs[wn*128 + nt*16 + (l&15)][kbase];
    #pragma unroll
    for (int mt=0;mt<4;mt++)
      #pragma unroll
      for (int nt=0;nt<8;nt++)
        acc[mt][nt] = __builtin_amdgcn_mfma_f32_16x16x32_bf16(a[mt], b[nt], acc[mt][nt], 0,0,0);
    __syncthreads();
  }
  #pragma unroll
  for (int nt=0;nt<8;nt++){
    int n = wn*128 + nt*16 + (l&15);
    float bias = bout[n];
    #pragma unroll
    for (int mt=0;mt<4;mt++){
      #pragma unroll
      for (int r=0;r<4;r++){
        int row = m0 + wm*64 + mt*16 + (l>>4)*4 + r;
        OUT[row*512 + n] = acc[mt][nt][r] + bias;
      }
    }
  }
}

// ---------------------------------------------------------------- launch
extern "C" void kernel_launch(void* const* d_in, const int* in_sizes, int n_in,
                              void* d_out, int out_size, void* d_ws, size_t ws_size,
                              hipStream_t stream){
  const float* x    = (const float*)d_in[0];
  const float* Wih  = (const float*)d_in[1];
  const float* Whh  = (const float*)d_in[2];
  const float* bih  = (const float*)d_in[3];
  const float* bhh  = (const float*)d_in[4];
  const float* Wout = (const float*)d_in[5];
  const float* bout = (const float*)d_in[6];

  const size_t XP_BYTES = 134217728ull;            // bf16 xp, [T][B][H]
  unsigned short* XP    = (unsigned short*)d_ws;
  unsigned short* WoutB = (unsigned short*)((char*)d_ws + XP_BYTES);
  unsigned short* HS    = (unsigned short*)d_out;  // hs bf16 lives in d_out
  float*          OUT   = (float*)d_out;

  k_cvt_wout<<<512, 256, 0, stream>>>(Wout, WoutB);
  dim3 g1(512, 8);
  k_gemm_xp<<<g1, 256, 0, stream>>>(x, Wih, bih, bhh, XP);
  // poison HS: 0xFF bytes -> every bf16 short is NaN (0xFFFF); tanh output
  // can never be NaN, so non-poison == final value (self-announcing data).
  (void)hipMemsetAsync(HS, 0xFF, 134217728ull, stream);
  k_rnn<<<64, 512, 0, stream>>>(Whh, XP, HS);
  k_gemm_out<<<512, 512, 0, stream>>>(HS, WoutB, bout, OUT);
}

// Round 17
// 2707.892 us; speedup vs baseline: 2.0206x; 1.1222x over previous
//
#include <hip/hip_runtime.h>

typedef __attribute__((ext_vector_type(8))) short s16x8;
typedef __attribute__((ext_vector_type(4))) float fx4;

static __device__ __forceinline__ unsigned short f2bf(float f){
  unsigned u = __float_as_uint(f);
  return (unsigned short)((u + 0x7fffu + ((u>>16)&1u)) >> 16);   // RNE
}
static __device__ __forceinline__ float bf2f(unsigned short s){
  return __uint_as_float(((unsigned)s)<<16);
}
// fast tanh: 1 - 2/(e^{2x}+1). Saturates to +-1, error ~1e-6 << bf16 ulp,
// can NEVER produce NaN (poison-safe). ~6 VALU ops vs libm tanhf's ~60.
static __device__ __forceinline__ float tanh_fast(float x){
  float e = __expf(2.0f*x);
  return 1.0f - 2.0f*__builtin_amdgcn_rcpf(e + 1.0f);
}
// Two 16B LLC-point loads (sc0+sc1 = agent scope: bypass L1 AND L2, read the
// LLC). asm volatile + memory clobber => re-executed every poll iteration.
// R4-R16 lessons: cross-XCD data is only HW-coherent at the LLC; polled
// addresses must be re-read at the LLC every iteration; validity must live IN
// the data (poison), not a separate flag; poll pressure must stay minimal
// (R11); nothing long-latency may share the poll's vmcnt(0) in a way that
// isn't also a useful commit-delay (R13); the rendezvous surface must be
// recently-written lines (R14); and the producer's 2B sc1 stores are already
// wave-coalesced into full 32B sectors (R16: WRITE_SIZE proves it).
static __device__ __forceinline__ void ld2_llc(const void* p0, const void* p1,
                                               uint4* o0, uint4* o1){
  uint4 a, b;
  asm volatile("global_load_dwordx4 %0, %2, off sc0 sc1\n\t"
               "global_load_dwordx4 %1, %3, off sc0 sc1\n\t"
               "s_waitcnt vmcnt(0)"
               : "=&v"(a), "=&v"(b) : "v"(p0), "v"(p1) : "memory");
  *o0 = a; *o1 = b;
}

// ---------------------------------------------------------------- W_out -> bf16
__global__ void k_cvt_wout(const float* __restrict__ w, unsigned short* __restrict__ o){
  int g = blockIdx.x*256 + threadIdx.x;
  int idx = g*4;
  float4 f = *(const float4*)(w + idx);
  unsigned u0 = (unsigned)f2bf(f.x) | ((unsigned)f2bf(f.y)<<16);
  unsigned u1 = (unsigned)f2bf(f.z) | ((unsigned)f2bf(f.w)<<16);
  *(uint2*)(o + idx) = make_uint2(u0, u1);
}

// ---------------------------------------------------------------- GEMM1: xp = x@W_ih^T + (b_ih+b_hh)
__global__ __launch_bounds__(256) void k_gemm_xp(
    const float* __restrict__ X, const float* __restrict__ Wih,
    const float* __restrict__ bih, const float* __restrict__ bhh,
    unsigned short* __restrict__ XP){
  __shared__ unsigned short As[128][40];
  __shared__ unsigned short Bs[128][40];
  const int bm = blockIdx.x, bn = blockIdx.y;
  const int tid = threadIdx.x, w = tid>>6, l = tid&63;
  const int wm = w>>1, wn = w&1;
  const int m0 = bm*128, n0 = bn*128;
  fx4 acc[4][4] = {};
  for (int kb = 0; kb < 512; kb += 32){
    #pragma unroll
    for (int q=0;q<4;q++){
      int f = tid + q*256;
      int row = f>>3, c4 = (f&7)*4;
      float4 v = *(const float4*)(X + (m0+row)*512 + kb + c4);
      unsigned u0 = (unsigned)f2bf(v.x) | ((unsigned)f2bf(v.y)<<16);
      unsigned u1 = (unsigned)f2bf(v.z) | ((unsigned)f2bf(v.w)<<16);
      *(uint2*)&As[row][c4] = make_uint2(u0,u1);
    }
    #pragma unroll
    for (int q=0;q<4;q++){
      int f = tid + q*256;
      int row = f>>3, c4 = (f&7)*4;
      float4 v = *(const float4*)(Wih + (n0+row)*512 + kb + c4);
      unsigned u0 = (unsigned)f2bf(v.x) | ((unsigned)f2bf(v.y)<<16);
      unsigned u1 = (unsigned)f2bf(v.z) | ((unsigned)f2bf(v.w)<<16);
      *(uint2*)&Bs[row][c4] = make_uint2(u0,u1);
    }
    __syncthreads();
    const int kbase = (l>>4)*8;
    s16x8 a[4], b[4];
    #pragma unroll
    for (int mt=0;mt<4;mt++) a[mt] = *(const s16x8*)&As[wm*64 + mt*16 + (l&15)][kbase];
    #pragma unroll
    for (int nt=0;nt<4;nt++) b[nt] = *(const s16x8*)&Bs[wn*64 + nt*16 + (l&15)][kbase];
    #pragma unroll
    for (int mt=0;mt<4;mt++)
      #pragma unroll
      for (int nt=0;nt<4;nt++)
        acc[mt][nt] = __builtin_amdgcn_mfma_f32_16x16x32_bf16(a[mt], b[nt], acc[mt][nt], 0,0,0);
    __syncthreads();
  }
  #pragma unroll
  for (int nt=0;nt<4;nt++){
    int n = n0 + wn*64 + nt*16 + (l&15);
    float bias = bih[n] + bhh[n];
    #pragma unroll
    for (int mt=0;mt<4;mt++){
      #pragma unroll
      for (int r=0;r<4;r++){
        int grow = m0 + wm*64 + mt*16 + (l>>4)*4 + r;   // = b*1024 + t
        int bb = grow >> 10, t = grow & 1023;
        XP[(t*64 + bb)*1024 + n] = f2bf(acc[mt][nt][r] + bias);
      }
    }
  }
}

// ---------------------------------------------------------------- recurrence
// FINAL (R12 optimum, 2320us k_rnn): poison-poll protocol + self-chunk
// bypass + tanh_fast, xp-prefetch-before-poll as commit-delay/overlap.
// Structural floor measured across R4-R16: ~2.2-2.4us/step = producer
// sc1-commit at LLC -> consumer poll detect -> LDS stage+barrier -> 32
// dependent MFMA + epilogue. All separable slack removed or proven
// already-optimal (R13: prefetch IS load-bearing; R14: mailbox adds HBM
// write-through; R16: commit already sector-packed).
// Protocol: HS pre-poisoned 0xFFFF (bf16 NaN; tanh can't produce it);
// write-once addresses; sc0+sc1 poll loads re-read the LLC every iteration;
// data self-announces (one LLC round trip carries detection AND payload).
// Self-chunk bypass: the WG produces 128 of the 1024 cols it consumes —
// epilogue writes those into the next step's LDS buffer (double-buffered,
// parity-disjoint) and those 64 threads never poll.
// Placement-independent, flag-free, deadlock-impossible.
__global__ __launch_bounds__(512) void k_rnn(
    const float* __restrict__ Whh, const unsigned short* __restrict__ XP,
    unsigned short* __restrict__ HS){
  __shared__ unsigned short hlds[2][8][1032];
  const int wg = blockIdx.x;
  const int gi = wg & 7;            // batch-group (8 rows)
  const int gj = wg >> 3;           // col block (128 cols)
  const int bi = gi*8, cj = gj*128;
  const int tid = threadIdx.x, w = tid>>6, l = tid&63;
  const int kbase = (l>>4)*8;

  // --- W_hh slice as resident MFMA B-fragments (128 VGPR/lane) ---
  const int col = cj + w*16 + (l&15);
  s16x8 wf[32];
  #pragma unroll
  for (int kk=0; kk<32; kk++){
    const float* p = Whh + col*1024 + kk*32 + kbase;
    float4 v0 = *(const float4*)p;
    float4 v1 = *(const float4*)(p+4);
    s16x8 s;
    s[0]=(short)f2bf(v0.x); s[1]=(short)f2bf(v0.y); s[2]=(short)f2bf(v0.z); s[3]=(short)f2bf(v0.w);
    s[4]=(short)f2bf(v1.x); s[5]=(short)f2bf(v1.y); s[6]=(short)f2bf(v1.z); s[7]=(short)f2bf(v1.w);
    wf[kk]=s;
  }

  const int ecol = cj + w*16 + (l&15);

  // --- step 0: h0 = tanh(xp_0); store global (self-announcing) + LDS buf0 ---
  {
    int e = tid*2;
    int row = e>>7, c = e&127;
    unsigned short h0 = f2bf(tanh_fast(bf2f(XP[(bi+row)*1024 + cj + c])));
    unsigned short h1 = f2bf(tanh_fast(bf2f(XP[(bi+row)*1024 + cj + c + 1])));
    unsigned pk = (unsigned)h0 | ((unsigned)h1<<16);
    __hip_atomic_store((unsigned*)&HS[((bi+row)*1024 + 0)*1024 + cj + c], pk,
                       __ATOMIC_RELAXED, __HIP_MEMORY_SCOPE_AGENT);
    hlds[0][row][cj + c]     = h0;       // own chunk pre-staged for step 1
    hlds[0][row][cj + c + 1] = h1;
  }

  const int srow = tid>>6, sc8 = (tid&63)*16;       // staging: thread owns (row, 32B)
  const bool ownchunk = ((unsigned)(sc8 - cj) < 128u); // chunk lies in own cols

  for (int s=1; s<1024; ++s){
    // xp prefetch (R12-proven position: before poll — acts as commit-delay
    // for the just-issued h stores and retires during the first poll iter)
    float xv[4];
    if (l < 32){
      #pragma unroll
      for (int r=0;r<4;r++)
        xv[r] = bf2f(XP[(s*64 + bi + (l>>4)*4 + r)*1024 + ecol]);
    }
    unsigned short (*buf)[1032]  = hlds[(s-1)&1];   // holds h_{s-1}
    unsigned short (*nbuf)[1032] = hlds[s&1];       // receives own h_s
    // --- poison-poll + stage h_{s-1}: peer chunks only (own pre-staged) ---
    if (!ownchunk){
      const unsigned short* rowp = HS + ((bi+srow)*1024 + (s-1))*1024 + sc8;
      uint4 v0, v1;
      for(;;){
        ld2_llc(rowp, rowp+8, &v0, &v1);
        unsigned bad = 0u;
        #pragma unroll
        for (int j=0;j<4;j++){
          unsigned u = ((unsigned*)&v0)[j];
          bad |= (unsigned)((u & 0xFFFFu) == 0xFFFFu) | (unsigned)(u >= 0xFFFF0000u);
        }
        #pragma unroll
        for (int j=0;j<4;j++){
          unsigned u = ((unsigned*)&v1)[j];
          bad |= (unsigned)((u & 0xFFFFu) == 0xFFFFu) | (unsigned)(u >= 0xFFFF0000u);
        }
        if (!bad) break;
      }
      *(uint4*)&buf[srow][sc8]     = v0;
      *(uint4*)&buf[srow][sc8 + 8] = v1;
    }
    __syncthreads();
    // --- 32 MFMA, 4 independent chains ---
    const int arow = (l&15)&7;
    fx4 ac0 = {0.f,0.f,0.f,0.f}, ac1 = ac0, ac2 = ac0, ac3 = ac0;
    #pragma unroll
    for (int kk=0;kk<32;kk+=4){
      s16x8 a0 = *(const s16x8*)&buf[arow][(kk+0)*32 + kbase];
      s16x8 a1 = *(const s16x8*)&buf[arow][(kk+1)*32 + kbase];
      s16x8 a2 = *(const s16x8*)&buf[arow][(kk+2)*32 + kbase];
      s16x8 a3 = *(const s16x8*)&buf[arow][(kk+3)*32 + kbase];
      ac0 = __builtin_amdgcn_mfma_f32_16x16x32_bf16(a0, wf[kk+0], ac0, 0,0,0);
      ac1 = __builtin_amdgcn_mfma_f32_16x16x32_bf16(a1, wf[kk+1], ac1, 0,0,0);
      ac2 = __builtin_amdgcn_mfma_f32_16x16x32_bf16(a2, wf[kk+2], ac2, 0,0,0);
      ac3 = __builtin_amdgcn_mfma_f32_16x16x32_bf16(a3, wf[kk+3], ac3, 0,0,0);
    }
    fx4 acc = (ac0+ac1)+(ac2+ac3);
    // --- epilogue: h_s = tanh(acc + xp); sc1 store (self-announcing,
    //     wave-coalesced into full 32B sectors per R16's WRITE_SIZE) +
    //     own-chunk write into next step's LDS buffer ---
    if (l < 32){
      #pragma unroll
      for (int r=0;r<4;r++){
        int row = (l>>4)*4 + r;
        unsigned short hv = f2bf(tanh_fast(acc[r] + xv[r]));
        __hip_atomic_store(&HS[((bi+row)*1024 + s)*1024 + ecol], hv,
                           __ATOMIC_RELAXED, __HIP_MEMORY_SCOPE_AGENT);
        nbuf[row][ecol] = hv;
      }
    }
    // no drain/flag/trailing barrier: next step's poll + barrier order it.
  }
}

// ---------------------------------------------------------------- GEMM2: out = hs@W_out^T + b_out
__global__ __launch_bounds__(512) void k_gemm_out(
    const unsigned short* __restrict__ HS, const unsigned short* __restrict__ WoutB,
    const float* __restrict__ bout, float* __restrict__ OUT){
  __shared__ unsigned short As[128][40];
  __shared__ unsigned short Bs[512][40];
  const int m0 = blockIdx.x*128;
  const int tid = threadIdx.x, w = tid>>6, l = tid&63;
  const int wm = w>>2, wn = w&3;
  fx4 acc[4][8] = {};
  for (int kb = 0; kb < 1024; kb += 32){
    {
      int row = tid>>2, c8 = (tid&3)*8;
      *(uint4*)&As[row][c8] = *(const uint4*)(HS + (m0+row)*1024 + kb + c8);
    }
    #pragma unroll
    for (int q=0;q<4;q++){
      int f = tid + q*512;
      int row = f>>2, c8 = (f&3)*8;
      *(uint4*)&Bs[row][c8] = *(const uint4*)(WoutB + row*1024 + kb + c8);
    }
    __syncthreads();
    const int kbase = (l>>4)*8;
    s16x8 a[4], b[8];
    #pragma unroll
    for (int mt=0;mt<4;mt++) a[mt] = *(const s16x8*)&As[wm*64 + mt*16 + (l&15)][kbase];
    #pragma unroll
    for (int nt=0;nt<8;nt++) b[nt] = *(const s16x8*)&Bs[wn*128 + nt*16 + (l&15)][kbase];
    #pragma unroll
    for (int mt=0;mt<4;mt++)
      #pragma unroll
      for (int nt=0;nt<8;nt++)
        acc[mt][nt] = __builtin_amdgcn_mfma_f32_16x16x32_bf16(a[mt], b[nt], acc[mt][nt], 0,0,0);
    __syncthreads();
  }
  #pragma unroll
  for (int nt=0;nt<8;nt++){
    int n = wn*128 + nt*16 + (l&15);
    float bias = bout[n];
    #pragma unroll
    for (int mt=0;mt<4;mt++){
      #pragma unroll
      for (int r=0;r<4;r++){
        int row = m0 + wm*64 + mt*16 + (l>>4)*4 + r;
        OUT[row*512 + n] = acc[mt][nt][r] + bias;
      }
    }
  }
}

// ---------------------------------------------------------------- launch
extern "C" void kernel_launch(void* const* d_in, const int* in_sizes, int n_in,
                              void* d_out, int out_size, void* d_ws, size_t ws_size,
                              hipStream_t stream){
  const float* x    = (const float*)d_in[0];
  const float* Wih  = (const float*)d_in[1];
  const float* Whh  = (const float*)d_in[2];
  const float* bih  = (const float*)d_in[3];
  const float* bhh  = (const float*)d_in[4];
  const float* Wout = (const float*)d_in[5];
  const float* bout = (const float*)d_in[6];

  const size_t XP_BYTES = 134217728ull;            // bf16 xp, [T][B][H]
  unsigned short* XP    = (unsigned short*)d_ws;
  unsigned short* WoutB = (unsigned short*)((char*)d_ws + XP_BYTES);
  unsigned short* HS    = (unsigned short*)d_out;  // hs bf16 lives in d_out
  float*          OUT   = (float*)d_out;

  k_cvt_wout<<<512, 256, 0, stream>>>(Wout, WoutB);
  dim3 g1(512, 8);
  k_gemm_xp<<<g1, 256, 0, stream>>>(x, Wih, bih, bhh, XP);
  // poison HS: 0xFF bytes -> every bf16 short is NaN (0xFFFF); tanh output
  // can never be NaN, so non-poison == final value (self-announcing data).
  (void)hipMemsetAsync(HS, 0xFF, 134217728ull, stream);
  k_rnn<<<64, 512, 0, stream>>>(Whh, XP, HS);
  k_gemm_out<<<512, 512, 0, stream>>>(HS, WoutB, bout, OUT);
}